// Round 1
// baseline (567.317 us; speedup 1.0000x reference)
//
#include <hip/hip_runtime.h>
#include <stddef.h>

#define TT 2048
#define NN 4096
#define LSEG 64
#define NSEG (TT / LSEG)   // 32
#define NBLK 16
#define TPB 256
#define MAXU 0xFFFFFFFFu
#define NOFIRE 0xFFFFFFFEu

// ---------------- Phase A: exact coupled simulation ----------------
// 16 blocks x 256 threads = 4096 threads, one neuron per thread, state in
// registers. Per coupled step: block-reduce min firing index, publish into
// slots[t][blk] (data-is-the-flag barrier), poll all 16 slots, apply jump.
// Exits at the first L-multiple step after nsp hits max_spikes; writes K' to hdr.
__global__ __launch_bounds__(TPB) void phaseA(
    const float* __restrict__ ts, const float* __restrict__ inp,
    const float* __restrict__ w, const float* __restrict__ v0,
    const float* __restrict__ i0, const float* __restrict__ mu,
    const float* __restrict__ s0u, const float* __restrict__ ru,
    const int* __restrict__ mx, float* __restrict__ ys,
    unsigned int* __restrict__ hdr, unsigned int* __restrict__ slots)
{
#pragma clang fp contract(off)
  const int tid = threadIdx.x;
  const int n = blockIdx.x * TPB + tid;
  const float dt = ts[1] - ts[0];
  const float mu1 = mu[0], mu2 = mu[1];
  const int maxs = mx[0];

  float v = v0[n];
  float i_nw = i0[n];                 // i, possibly missing last step's w add
  float s = logf(s0u[n] + 1e-12f) - 0.01f;
  float wv = 0.0f;
  bool applyw = false;
  float inpv = inp[n];                // row 0 prefetched
  float ruv  = ru[n];
  int nsp = 0;
  int t_stop = TT;

  __shared__ unsigned int sh_w[TPB / 64];
  __shared__ unsigned int sh_b;

  for (int t = 0; t < TT; ++t) {
    // prefetch next row (consumed next iteration; hides HBM latency behind barrier)
    float inpv_n = 0.0f, ruv_n = 0.0f;
    if (t + 1 < TT) {
      inpv_n = inp[(size_t)(t + 1) * NN + n];
      ruv_n  = ru[(size_t)(t + 1) * NN + n];
    }
    float logru = logf(ruv + 1e-12f) - 0.01f;
    float sig = 1.0f / (1.0f + expf(-v));
    float sn = s + dt * sig;
    bool ev = sn >= 0.0f;
    bool coupled = (nsp < maxs);

    if (coupled) {
      unsigned int m = ev ? (unsigned int)n : NOFIRE;
#pragma unroll
      for (int off = 32; off > 0; off >>= 1) {
        unsigned int o = (unsigned int)__shfl_down((int)m, off, 64);
        m = m < o ? m : o;
      }
      if ((tid & 63) == 0) sh_w[tid >> 6] = m;
      __syncthreads();
      if (tid == 0) {
        unsigned int bm = sh_w[0];
        for (int k = 1; k < TPB / 64; ++k) bm = bm < sh_w[k] ? bm : sh_w[k];
        __hip_atomic_store(&slots[(size_t)t * NBLK + blockIdx.x], bm,
                           __ATOMIC_RELAXED, __HIP_MEMORY_SCOPE_AGENT);
      }
    }

    // resolve last step's pending w-row add (load issued a full iteration ago)
    float i_full = applyw ? (i_nw + wv) : i_nw;
    // deferred store of ys[t-1] (now that i is final)
    if (t > 0) {
      size_t o = ((size_t)(t - 1) * NN + n) * 3;
      ys[o] = v; ys[o + 1] = i_full; ys[o + 2] = s;
    }
    // step-t drift (numpy op order, no contraction)
    float vn  = v + dt * (mu1 * (i_full - v) + mu1 * inpv);
    float in_ = i_full + dt * (-mu2 * i_full);

    unsigned int gm = NOFIRE;
    if (coupled) {
      if (tid == 0) {
        unsigned int res = NOFIRE;
        long guard = 0;
        for (;;) {
          unsigned int mn = MAXU;
          bool all = true;
#pragma unroll
          for (int bk = 0; bk < NBLK; ++bk) {
            unsigned int x = __hip_atomic_load(&slots[(size_t)t * NBLK + bk],
                                               __ATOMIC_RELAXED,
                                               __HIP_MEMORY_SCOPE_AGENT);
            all = all && (x != MAXU);
            mn = mn < x ? mn : x;
          }
          if (all || ++guard > (1L << 21)) { res = mn; break; }
        }
        sh_b = res;
      }
      __syncthreads();
      gm = sh_b;
    }

    bool fire = coupled && (gm < (unsigned int)NN);
    applyw = false;
    if (fire) {
      nsp += 1;
      wv = w[(size_t)gm * NN + n];   // issue gather; consumed NEXT iteration
      if (ev) { v = vn - 1.0f; s = logru; }
      else    { v = vn; s = sn; applyw = true; }
    } else {
      v = vn; s = sn;
    }
    i_nw = in_;
    inpv = inpv_n; ruv = ruv_n;

    if (nsp >= maxs && ((t + 1) & (LSEG - 1)) == 0) { t_stop = t + 1; break; }
  }

  // flush final deferred store
  {
    float i_full = applyw ? (i_nw + wv) : i_nw;
    size_t o = ((size_t)(t_stop - 1) * NN + n) * 3;
    ys[o] = v; ys[o + 1] = i_full; ys[o + 2] = s;
  }
  if (n == 0) hdr[0] = (unsigned int)t_stop;
}

// ---------------- Phase B: decoupled closed-form tail ----------------
// P1: per (neuron, segment): C = sum_j a^(L-1-j) * b * (i_j + inp_j), i_j geometric.
__global__ __launch_bounds__(TPB) void p1_segc(
    const float* __restrict__ ts, const float* __restrict__ inp,
    const float* __restrict__ mu, const float* __restrict__ ys,
    const unsigned int* __restrict__ hdr, float* __restrict__ buf1)
{
  unsigned int Kp = hdr[0];
  unsigned int g0 = Kp / LSEG;
  unsigned int g = blockIdx.x >> 4;
  if (g < g0) return;
  int n = (blockIdx.x & 15) * TPB + threadIdx.x;
  float dt = ts[1] - ts[0];
  float mu1 = mu[0], mu2 = mu[1];
  float a = 1.0f - dt * mu1, b = dt * mu1, r = 1.0f - dt * mu2;
  float ibase = ys[((size_t)(Kp - 1) * NN + n) * 3 + 1];
  float ij = ibase * powf(r, (float)((int)(g * LSEG) - (int)Kp));
  float c = 0.0f;
  size_t base = (size_t)(g * LSEG) * NN + n;
  for (int j = 0; j < LSEG; ++j) {
    float x = inp[base + (size_t)j * NN];
    c = a * c + b * (ij + x);
    ij *= r;
  }
  buf1[(size_t)g * NN + n] = c;
}

// P2: per neuron, scan segment-boundary v:  v_{g+1} = a^L v_g + C_g (in place -> Vb)
__global__ __launch_bounds__(TPB) void p2_scanv(
    const float* __restrict__ ts, const float* __restrict__ mu,
    const float* __restrict__ ys, const unsigned int* __restrict__ hdr,
    float* __restrict__ buf1)
{
  unsigned int Kp = hdr[0];
  unsigned int g0 = Kp / LSEG;
  if (g0 >= NSEG) return;
  int n = blockIdx.x * TPB + threadIdx.x;
  float dt = ts[1] - ts[0];
  float mu1 = mu[0];
  float a = 1.0f - dt * mu1;
  float aL = a;
  for (int k = 0; k < 6; ++k) aL *= aL;   // a^64
  float v = ys[((size_t)(Kp - 1) * NN + n) * 3 + 0];
  for (unsigned int g = g0; g < NSEG; ++g) {
    float cg = buf1[(size_t)g * NN + n];
    buf1[(size_t)g * NN + n] = v;
    v = aL * v + cg;
  }
}

// P3: per (neuron, segment): replay 64 steps; write v,i and local s-prefix to ys;
// stash segment sigma-sum into buf2.
__global__ __launch_bounds__(TPB) void p3_seg(
    const float* __restrict__ ts, const float* __restrict__ inp,
    const float* __restrict__ mu, const unsigned int* __restrict__ hdr,
    const float* __restrict__ buf1, float* __restrict__ buf2,
    float* __restrict__ ys)
{
  unsigned int Kp = hdr[0];
  unsigned int g0 = Kp / LSEG;
  unsigned int g = blockIdx.x >> 4;
  if (g < g0) return;
  int n = (blockIdx.x & 15) * TPB + threadIdx.x;
  float dt = ts[1] - ts[0];
  float mu1 = mu[0], mu2 = mu[1];
  float r = 1.0f - dt * mu2;
  float v = buf1[(size_t)g * NN + n];
  float ibase = ys[((size_t)(Kp - 1) * NN + n) * 3 + 1];
  float i = ibase * powf(r, (float)((int)(g * LSEG) - (int)Kp));
  float sl = 0.0f;
  for (int j = 0; j < LSEG; ++j) {
    size_t t = (size_t)g * LSEG + j;
    float x = inp[t * NN + n];
    float sig = 1.0f / (1.0f + expf(-v));
    sl = sl + dt * sig;
    float vn  = v + dt * (mu1 * (i - v) + mu1 * x);
    float in_ = i + dt * (-mu2 * i);
    size_t o = (t * NN + n) * 3;
    ys[o] = vn; ys[o + 1] = in_; ys[o + 2] = sl;
    v = vn; i = in_;
  }
  buf2[(size_t)g * NN + n] = sl;
}

// P4: per neuron, scan sigma-sums -> s at segment starts (in place -> Sb)
__global__ __launch_bounds__(TPB) void p4_scans(
    const float* __restrict__ ys, const unsigned int* __restrict__ hdr,
    float* __restrict__ buf2)
{
  unsigned int Kp = hdr[0];
  unsigned int g0 = Kp / LSEG;
  if (g0 >= NSEG) return;
  int n = blockIdx.x * TPB + threadIdx.x;
  float s = ys[((size_t)(Kp - 1) * NN + n) * 3 + 2];
  for (unsigned int g = g0; g < NSEG; ++g) {
    float t = buf2[(size_t)g * NN + n];
    buf2[(size_t)g * NN + n] = s;
    s += t;
  }
}

// P5: ys[t][n].s += Sb[t/L][n] for t >= K'
__global__ __launch_bounds__(TPB) void p5_fixs(
    const unsigned int* __restrict__ hdr, const float* __restrict__ buf2,
    float* __restrict__ ys)
{
  unsigned int Kp = hdr[0];
  size_t e = (size_t)Kp * NN + (size_t)blockIdx.x * TPB + threadIdx.x;
  if (e >= (size_t)TT * NN) return;
  unsigned int t = (unsigned int)(e >> 12);        // /NN
  unsigned int n = (unsigned int)(e & (NN - 1));
  unsigned int g = t >> 6;                         // /LSEG
  ys[e * 3 + 2] += buf2[(size_t)g * NN + n];
}

extern "C" void kernel_launch(void* const* d_in, const int* in_sizes, int n_in,
                              void* d_out, int out_size, void* d_ws, size_t ws_size,
                              hipStream_t stream)
{
  (void)in_sizes; (void)n_in; (void)out_size; (void)ws_size;
  const float* ts  = (const float*)d_in[0];
  const float* inp = (const float*)d_in[1];
  const float* w   = (const float*)d_in[2];
  const float* v0  = (const float*)d_in[3];
  const float* i0  = (const float*)d_in[4];
  const float* mu  = (const float*)d_in[5];
  const float* s0u = (const float*)d_in[6];
  const float* ru  = (const float*)d_in[7];
  const int*   mx  = (const int*)d_in[8];
  float* ys = (float*)d_out;

  char* wsb = (char*)d_ws;
  unsigned int* hdr   = (unsigned int*)wsb;                       // 64 B used
  unsigned int* slots = (unsigned int*)(wsb + 1024);              // T*16*4 = 128 KB
  float* buf1 = (float*)(wsb + 1024 + (size_t)TT * NBLK * 4);     // 512 KB
  float* buf2 = buf1 + (size_t)NSEG * NN;                         // 512 KB

  // barrier slots must start as 0xFFFFFFFF (= "not arrived")
  hipMemsetAsync(slots, 0xFF, (size_t)TT * NBLK * 4, stream);

  phaseA<<<NBLK, TPB, 0, stream>>>(ts, inp, w, v0, i0, mu, s0u, ru, mx, ys, hdr, slots);
  p1_segc<<<NSEG * 16, TPB, 0, stream>>>(ts, inp, mu, ys, hdr, buf1);
  p2_scanv<<<NN / TPB, TPB, 0, stream>>>(ts, mu, ys, hdr, buf1);
  p3_seg<<<NSEG * 16, TPB, 0, stream>>>(ts, inp, mu, hdr, buf1, buf2, ys);
  p4_scans<<<NN / TPB, TPB, 0, stream>>>(ys, hdr, buf2);
  p5_fixs<<<(TT - 128) * NN / TPB, TPB, 0, stream>>>(hdr, buf2, ys);
}